// Round 1
// 732.342 us; speedup vs baseline: 1.0751x; 1.0751x over previous
//
#include <hip/hip_runtime.h>
#include <stdint.h>

typedef unsigned short u16;
typedef __bf16 bf16t;
typedef bf16t bf16x8 __attribute__((ext_vector_type(8)));
typedef float f32x4 __attribute__((ext_vector_type(4)));
typedef unsigned long long ull;

#define NROWS 100000
#define DD 512
#define QD 128
#define KSEL 20000
#define NB 1563   // ceil(100000/64)

// ---------- helpers ----------
__device__ __forceinline__ uint32_t fmono(float x){
  uint32_t u = __float_as_uint(x);
  return (u & 0x80000000u) ? ~u : (u | 0x80000000u);
}
__device__ __forceinline__ float finv(uint32_t k){  // inverse of fmono
  uint32_t u = (k & 0x80000000u) ? (k & 0x7fffffffu) : ~k;
  return __uint_as_float(u);
}
__device__ __forceinline__ u16 f2bf(float x){  // RNE float->bf16 bits
  uint32_t u = __float_as_uint(x);
  u += 0x7fffu + ((u >> 16) & 1u);
  return (u16)(u >> 16);
}
__device__ __forceinline__ uint32_t pkbf(float a, float b){
  return (uint32_t)f2bf(a) | ((uint32_t)f2bf(b) << 16);
}

struct Scal {
  uint32_t keyT;
  float Z;
  uint32_t pad[14];
};

#define MFMA16(A,B,C) __builtin_amdgcn_mfma_f32_16x16x32_bf16(A,B,C,0,0,0)

// ---------- k_conv: fp32 weights -> bf16 (proven); also zero hist / cmax ----------
__global__ void k_conv(const float* __restrict__ Wl, const float* __restrict__ Wv,
                       const float* __restrict__ Wq, u16* __restrict__ wl_bf, u16* __restrict__ wvq_bf,
                       uint32_t* __restrict__ hist, ull* __restrict__ cmax){
  int idx = blockIdx.x*256 + threadIdx.x;          // 589824 total
  if (idx < 65536) hist[idx] = 0u;
  if (idx == 0){ cmax[0] = 0ull; cmax[1] = 0ull; }
  if (idx < 262144) wl_bf[idx] = f2bf(Wl[idx]);
  int e = idx - 262144;
  if (e >= 0) wvq_bf[e] = f2bf(e < 262144 ? Wv[e] : Wq[e - 262144]);
}

// ---------- k_sel1: multi-block 16-bit histogram of fmono(preds) + c-argmax partials ----------
__global__ void k_sel1(const float* __restrict__ preds, const float* __restrict__ c,
                       uint32_t* __restrict__ hist, ull* __restrict__ cmax){
  __shared__ ull kr0[4], kr1[4];
  const int t = threadIdx.x;                // 256
  const int gid = blockIdx.x*256 + t;       // grid 256 blocks -> 65536 threads
  const int lane = t & 63;

  const float4* p4 = (const float4*)preds;
  for (int i = gid; i < 25000; i += 65536){
    float4 v = p4[i];
    atomicAdd(&hist[fmono(v.x) >> 16], 1u);
    atomicAdd(&hist[fmono(v.y) >> 16], 1u);
    atomicAdd(&hist[fmono(v.z) >> 16], 1u);
    atomicAdd(&hist[fmono(v.w) >> 16], 1u);
  }

  ull k0 = 0ull, k1 = 0ull;
  const float4* c4 = (const float4*)c;
  for (int i = gid; i < 50000; i += 65536){
    float4 v = c4[i];                       // rows 2i (x=c0,y=c1), 2i+1 (z=c0,w=c1)
    uint32_t r0 = 2u*i, r1 = 2u*i + 1u;
    ull a0 = ((ull)fmono(v.x) << 32) | (ull)(~r0);
    ull a1 = ((ull)fmono(v.z) << 32) | (ull)(~r1);
    ull b0 = ((ull)fmono(v.y) << 32) | (ull)(~r0);
    ull b1 = ((ull)fmono(v.w) << 32) | (ull)(~r1);
    if (a0 > k0) k0 = a0;
    if (a1 > k0) k0 = a1;
    if (b0 > k1) k1 = b0;
    if (b1 > k1) k1 = b1;
  }
  #pragma unroll
  for (int off = 32; off; off >>= 1){
    ull o0 = __shfl_xor(k0, off); if (o0 > k0) k0 = o0;
    ull o1 = __shfl_xor(k1, off); if (o1 > k1) k1 = o1;
  }
  if (lane == 0){ kr0[t >> 6] = k0; kr1[t >> 6] = k1; }
  __syncthreads();
  if (t == 0){
    ull m0 = kr0[0], m1 = kr1[0];
    #pragma unroll
    for (int w = 1; w < 4; ++w){
      if (kr0[w] > m0) m0 = kr0[w];
      if (kr1[w] > m1) m1 = kr1[w];
    }
    atomicMax(&cmax[0], m0);
    atomicMax(&cmax[1], m1);
  }
}

// ---------- k_prep2: one block — scan hist, exact keyT, Z, m_feats, q_max ----------
#define CAND_CAP 8192
__launch_bounds__(1024)
__global__ void k_prep2(const float* __restrict__ preds, const float* __restrict__ feats,
                        const float* __restrict__ Wl, const float* __restrict__ bl,
                        const float* __restrict__ Wq, const float* __restrict__ bq,
                        const uint32_t* __restrict__ hist, const ull* __restrict__ cmax,
                        Scal* __restrict__ sc, float* __restrict__ qmv){
  __shared__ uint32_t cand[CAND_CAP];
  __shared__ uint32_t wsum[16], woff[16];
  __shared__ float zred[16];
  __shared__ uint32_t s_B, s_cumBelow, s_keyT, candN;
  __shared__ float s_Z;
  __shared__ uint32_t s_mi[2];
  __shared__ float fmX[2][512];
  __shared__ float fmF[2][512];
  const int t = threadIdx.x;
  const int lane = t & 63, wv = t >> 6;

  if (t == 0){
    candN = 0;
    s_mi[0] = ~(uint32_t)(cmax[0] & 0xffffffffull);
    s_mi[1] = ~(uint32_t)(cmax[1] & 0xffffffffull);
  }

  // ---- parallel scan of 65536-bin histogram; find bucket containing rank KSEL ----
  const int b0 = t*64;
  uint32_t local = 0;
  {
    const uint4* h4 = (const uint4*)(hist + b0);
    #pragma unroll 4
    for (int q = 0; q < 16; ++q){ uint4 hv = h4[q]; local += hv.x + hv.y + hv.z + hv.w; }
  }
  uint32_t x = local;
  #pragma unroll
  for (int off = 1; off < 64; off <<= 1){
    uint32_t y = __shfl_up(x, off);
    if (lane >= off) x += y;
  }
  if (lane == 63) wsum[wv] = x;
  __syncthreads();
  if (t == 0){
    uint32_t cum = 0;
    for (int w = 0; w < 16; ++w){ woff[w] = cum; cum += wsum[w]; }
  }
  __syncthreads();
  uint32_t excl = x - local + woff[wv];       // exclusive prefix of this thread's 64 bins
  if (excl < KSEL && excl + local >= KSEL){   // unique crossing thread
    uint32_t cum = excl;
    for (int b = 0; b < 64; ++b){
      uint32_t h = hist[b0 + b];
      if (cum + h >= KSEL){ s_B = (uint32_t)(b0 + b); s_cumBelow = cum; break; }
      cum += h;
    }
  }
  __syncthreads();
  const uint32_t B = s_B;

  // ---- one pass over preds: sum exp over buckets > B; collect bucket-B candidates ----
  float sA = 0.f;
  const float4* p4 = (const float4*)preds;
  for (int i = t; i < 25000; i += 1024){
    float4 v = p4[i];
    float vv[4] = {v.x, v.y, v.z, v.w};
    #pragma unroll
    for (int e = 0; e < 4; ++e){
      uint32_t k = fmono(vv[e]);
      uint32_t bb = k >> 16;
      if (bb > B){
        sA += __expf(vv[e]);
      } else if (bb == B){
        uint32_t idx = atomicAdd(&candN, 1u);
        if (idx < CAND_CAP) cand[idx] = k;
      }
    }
  }
  #pragma unroll
  for (int off = 32; off; off >>= 1) sA += __shfl_xor(sA, off);
  if (lane == 0) zred[wv] = sA;
  __syncthreads();

  // ---- exact rank select among candidates (O(n^2), n ~ few hundred) ----
  const uint32_t n = candN < CAND_CAP ? candN : CAND_CAP;
  const uint32_t r = KSEL - s_cumBelow;       // 1-indexed rank within bucket
  for (uint32_t i = t; i < n; i += 1024){
    uint32_t ki = cand[i];
    uint32_t less = 0, eq = 0;
    for (uint32_t j = 0; j < n; ++j){
      uint32_t kj = cand[j];
      less += (kj < ki) ? 1u : 0u;
      eq   += (kj == ki) ? 1u : 0u;
    }
    if (less < r && r <= less + eq) s_keyT = ki;
  }
  __syncthreads();
  const uint32_t keyT = s_keyT;

  // ---- add exp of candidates strictly above keyT ----
  float sCA = 0.f;
  for (uint32_t i = t; i < n; i += 1024){
    uint32_t k = cand[i];
    if (k > keyT) sCA += __expf(finv(k));
  }
  #pragma unroll
  for (int off = 32; off; off >>= 1) sCA += __shfl_xor(sCA, off);
  if (lane == 0) zred[wv] += sCA;
  __syncthreads();
  if (t == 0){
    float Z = (float)KSEL;                    // exp(0)=1 for each of the KSEL zeroed entries
    for (int w = 0; w < 16; ++w) Z += zred[w];
    s_Z = Z;
    sc->keyT = keyT; sc->Z = Z;
  }
  __syncthreads();

  // ---- load the 2 argmax feats rows ----
  {
    int j = t >> 9, col = t & 511;
    fmX[j][col] = feats[(size_t)s_mi[j]*DD + col];
  }
  __syncthreads();

  // ---- exact fp32 m_feats ----
  {
    int nn = t >> 1, h = t & 1;
    const float4* wr4 = (const float4*)(Wl + (size_t)nn*DD + h*256);
    const float4* x04 = (const float4*)(&fmX[0][h*256]);
    const float4* x14 = (const float4*)(&fmX[1][h*256]);
    float a0 = 0.f, a1 = 0.f;
    #pragma unroll 4
    for (int k = 0; k < 64; ++k){
      float4 w = wr4[k], u = x04[k], v = x14[k];
      a0 += u.x*w.x + u.y*w.y + u.z*w.z + u.w*w.w;
      a1 += v.x*w.x + v.y*w.y + v.z*w.z + v.w*w.w;
    }
    a0 += __shfl_xor(a0, 1);
    a1 += __shfl_xor(a1, 1);
    if (h == 0){
      float Z = s_Z;
      float p0 = preds[s_mi[0]]; float q0 = (fmono(p0) <= keyT) ? 0.f : p0;
      float g0 = 1.f + __expf(q0) / Z;
      float p1 = preds[s_mi[1]]; float q1 = (fmono(p1) <= keyT) ? 0.f : p1;
      float g1 = 1.f + __expf(q1) / Z;
      float v0 = bl[nn] + g0*a0; fmF[0][nn] = v0 > 0.f ? v0 : 0.f;
      float v1 = bl[nn] + g1*a1; fmF[1][nn] = v1 > 0.f ? v1 : 0.f;
    }
  }
  __syncthreads();

  // ---- q_max ----
  if (t < 256){
    int q = t & 127, j = t >> 7;
    const float4* wr4 = (const float4*)(Wq + (size_t)q*DD);
    const float4* x4  = (const float4*)(fmF[j]);
    float a0 = 0.f, a1 = 0.f;
    #pragma unroll 4
    for (int k = 0; k < 128; k += 2){
      float4 w0 = wr4[k], u0 = x4[k];
      float4 w1 = wr4[k+1], u1 = x4[k+1];
      a0 += u0.x*w0.x + u0.y*w0.y + u0.z*w0.z + u0.w*w0.w;
      a1 += u1.x*w1.x + u1.y*w1.y + u1.z*w1.z + u1.w*w1.w;
    }
    qmv[j*QD + q] = tanhf(bq[q] + a0 + a1);
  }
}

// ---------- weight chunk source: linear chunk index ci = 0..143 ----------
__device__ __forceinline__ const u16* chunk_src(const u16* __restrict__ wl,
                                                const u16* __restrict__ wvq,
                                                int ci, int r, int p){
  if (ci < 64){
    int nt = ci >> 4, kc = ci & 15;
    return wl + (size_t)(nt*128 + r)*DD + kc*32 + p*16;
  }
  int c2 = ci - 64;
  int nt2 = c2 >> 4, kc = c2 & 15;
  int colbase = (nt2 == 0) ? 512 : (nt2 - 1)*128;
  return wvq + (size_t)(colbase + r)*DD + kc*32 + p*16;
}

// ---------- k_fused: M=64, 2x2 wave grid, wave tile 32x64 ----------
// LDS (u16): AF [64][520] @0 (33280); Wb [128][40] @33280 (5120) -> 38400 u16 = 76.8KB
// sred overlays Wb (256 f32); Ef separate 128 f32.
__launch_bounds__(256, 2)
__global__ void k_fused(const float* __restrict__ feats, const float* __restrict__ preds,
                        const u16* __restrict__ wl, const u16* __restrict__ wvq,
                        const float* __restrict__ bl, const float* __restrict__ bv,
                        const float* __restrict__ bq, const float* __restrict__ qmv,
                        const Scal* __restrict__ sc,
                        float* __restrict__ gpart, float* __restrict__ gpartE,
                        float* __restrict__ Aout){
  __shared__ __align__(16) u16 lds[38400];
  __shared__ __align__(16) float Ef[128];
  u16* AF = lds;                        // [64][520]
  u16* Wb = lds + 33280;                // [128][40]
  float* sred = (float*)(lds + 33280);  // overlay: [64 rows][2 j][2 wn]
  const int tid = threadIdx.x;
  const int lane = tid & 63, quad = lane >> 4, l16 = lane & 15;
  const int wave = tid >> 6, wm = wave >> 1, wn = wave & 1;
  const long i0 = (long)blockIdx.x * 64;
  const uint32_t keyT = sc->keyT;
  const float Z = sc->Z;

  // ---- stage gX tile (64 x 512) into LDS as bf16, g folded; row = lane ----
  {
    int row = lane;
    long ir = i0 + row; if (ir >= NROWS) ir = NROWS - 1;
    float p = preds[ir];
    float pm = (fmono(p) <= keyT) ? 0.f : p;
    float g = 1.f + __expf(pm) / Z;
    const float4* src = (const float4*)(feats + ir*DD + wave*128);
    u16* dst = AF + row*520 + wave*128;
    #pragma unroll
    for (int j = 0; j < 16; ++j){
      float4 a = src[2*j], b = src[2*j + 1];
      uint4 pk;
      pk.x = pkbf(a.x*g, a.y*g); pk.y = pkbf(a.z*g, a.w*g);
      pk.z = pkbf(b.x*g, b.y*g); pk.w = pkbf(b.z*g, b.w*g);
      *(uint4*)(dst + j*8) = pk;
    }
  }

  const int rS = tid >> 1, pS = tid & 1;
  u16* wdst = Wb + rS*40 + pS*16;
  uint4 w0, w1;
  { const u16* sp = chunk_src(wl, wvq, 0, rS, pS); w0 = *(const uint4*)sp; w1 = *(const uint4*)(sp + 8); }

  f32x4 acc[2][4];
  uint32_t pkF[4][16];
  int ci = 0;

  // ---- stage 1: f = relu(gX @ Wl^T + bl) -> pkF registers ----
  for (int nt = 0; nt < 4; ++nt){
    #pragma unroll
    for (int mi = 0; mi < 2; ++mi)
      #pragma unroll
      for (int ni = 0; ni < 4; ++ni) acc[mi][ni] = (f32x4){0.f,0.f,0.f,0.f};
    for (int kc = 0; kc < 16; ++kc, ++ci){
      __syncthreads();
      *(uint4*)wdst = w0; *(uint4*)(wdst + 8) = w1;
      __syncthreads();
      if (ci < 143){
        const u16* sp = chunk_src(wl, wvq, ci + 1, rS, pS);
        w0 = *(const uint4*)sp; w1 = *(const uint4*)(sp + 8);
      }
      bf16x8 a0 = *(const bf16x8*)&AF[(wm*32 + l16)*520 + kc*32 + quad*8];
      bf16x8 a1 = *(const bf16x8*)&AF[(wm*32 + 16 + l16)*520 + kc*32 + quad*8];
      bf16x8 b0 = *(const bf16x8*)&Wb[(wn*64 +  0 + l16)*40 + quad*8];
      bf16x8 b1 = *(const bf16x8*)&Wb[(wn*64 + 16 + l16)*40 + quad*8];
      bf16x8 b2 = *(const bf16x8*)&Wb[(wn*64 + 32 + l16)*40 + quad*8];
      bf16x8 b3 = *(const bf16x8*)&Wb[(wn*64 + 48 + l16)*40 + quad*8];
      acc[0][0] = MFMA16(a0, b0, acc[0][0]);
      acc[0][1] = MFMA16(a0, b1, acc[0][1]);
      acc[0][2] = MFMA16(a0, b2, acc[0][2]);
      acc[0][3] = MFMA16(a0, b3, acc[0][3]);
      acc[1][0] = MFMA16(a1, b0, acc[1][0]);
      acc[1][1] = MFMA16(a1, b1, acc[1][1]);
      acc[1][2] = MFMA16(a1, b2, acc[1][2]);
      acc[1][3] = MFMA16(a1, b3, acc[1][3]);
    }
    #pragma unroll
    for (int ni = 0; ni < 4; ++ni){
      float bb = bl[nt*128 + wn*64 + ni*16 + l16];
      #pragma unroll
      for (int mi = 0; mi < 2; ++mi){
        float e0 = acc[mi][ni][0] + bb; e0 = e0 > 0.f ? e0 : 0.f;
        float e1 = acc[mi][ni][1] + bb; e1 = e1 > 0.f ? e1 : 0.f;
        float e2 = acc[mi][ni][2] + bb; e2 = e2 > 0.f ? e2 : 0.f;
        float e3 = acc[mi][ni][3] + bb; e3 = e3 > 0.f ? e3 : 0.f;
        pkF[nt][mi*8 + ni*2 + 0] = pkbf(e0, e1);
        pkF[nt][mi*8 + ni*2 + 1] = pkbf(e2, e3);
      }
    }
  }

  // ---- transpose pkF (C-layout) -> F tile in AF (A-operand layout) ----
  __syncthreads();
  #pragma unroll
  for (int nt = 0; nt < 4; ++nt)
    #pragma unroll
    for (int ni = 0; ni < 4; ++ni)
      #pragma unroll
      for (int mi = 0; mi < 2; ++mi){
        int col = nt*128 + wn*64 + ni*16 + l16;
        int r0 = (wm*32 + mi*16 + quad*4)*520 + col;
        uint32_t x = pkF[nt][mi*8 + ni*2], y = pkF[nt][mi*8 + ni*2 + 1];
        AF[r0]        = (u16)x;
        AF[r0 + 520]  = (u16)(x >> 16);
        AF[r0 + 1040] = (u16)y;
        AF[r0 + 1560] = (u16)(y >> 16);
      }

  // ---- stage 2: [Q|V] = f @ W^T ; Q first (nt2=0 -> e), then V weighted ----
  for (int nt2 = 0; nt2 < 5; ++nt2){
    #pragma unroll
    for (int mi = 0; mi < 2; ++mi)
      #pragma unroll
      for (int ni = 0; ni < 4; ++ni) acc[mi][ni] = (f32x4){0.f,0.f,0.f,0.f};
    for (int kc = 0; kc < 16; ++kc, ++ci){
      __syncthreads();
      *(uint4*)wdst = w0; *(uint4*)(wdst + 8) = w1;
      __syncthreads();
      if (ci < 143){
        const u16* sp = chunk_src(wl, wvq, ci + 1, rS, pS);
        w0 = *(const uint4*)sp; w1 = *(const uint4*)(sp + 8);
      }
      bf16x8 a0 = *(const bf16x8*)&AF[(wm*32 + l16)*520 + kc*32 + quad*8];
      bf16x8 a1 = *(const bf16x8*)&AF[(wm*32 + 16 + l16)*520 + kc*32 + quad*8];
      bf16x8 b0 = *(const bf16x8*)&Wb[(wn*64 +  0 + l16)*40 + quad*8];
      bf16x8 b1 = *(const bf16x8*)&Wb[(wn*64 + 16 + l16)*40 + quad*8];
      bf16x8 b2 = *(const bf16x8*)&Wb[(wn*64 + 32 + l16)*40 + quad*8];
      bf16x8 b3 = *(const bf16x8*)&Wb[(wn*64 + 48 + l16)*40 + quad*8];
      acc[0][0] = MFMA16(a0, b0, acc[0][0]);
      acc[0][1] = MFMA16(a0, b1, acc[0][1]);
      acc[0][2] = MFMA16(a0, b2, acc[0][2]);
      acc[0][3] = MFMA16(a0, b3, acc[0][3]);
      acc[1][0] = MFMA16(a1, b0, acc[1][0]);
      acc[1][1] = MFMA16(a1, b1, acc[1][1]);
      acc[1][2] = MFMA16(a1, b2, acc[1][2]);
      acc[1][3] = MFMA16(a1, b3, acc[1][3]);
    }
    if (nt2 == 0){
      // ---- Q epilogue: tanh, dot with qmv, e = exp(score/sqrt(128)) ----
      float p0[2][4], p1[2][4];
      #pragma unroll
      for (int mi = 0; mi < 2; ++mi)
        #pragma unroll
        for (int e = 0; e < 4; ++e){ p0[mi][e] = 0.f; p1[mi][e] = 0.f; }
      #pragma unroll
      for (int ni = 0; ni < 4; ++ni){
        int qc = wn*64 + ni*16 + l16;
        float bqv = bq[qc], q0 = qmv[qc], q1 = qmv[QD + qc];
        #pragma unroll
        for (int mi = 0; mi < 2; ++mi)
          #pragma unroll
          for (int e = 0; e < 4; ++e){
            float tq = tanhf(acc[mi][ni][e] + bqv);
            p0[mi][e] += tq * q0;
            p1[mi][e] += tq * q1;
          }
      }
      #pragma unroll
      for (int off = 1; off <= 8; off <<= 1)
        #pragma unroll
        for (int mi = 0; mi < 2; ++mi)
          #pragma unroll
          for (int e = 0; e < 4; ++e){
            p0[mi][e] += __shfl_xor(p0[mi][e], off);
            p1[mi][e] += __shfl_xor(p1[mi][e], off);
          }
      __syncthreads();   // Wb MFMA reads done before sred overlay write
      if (l16 == 0){
        #pragma unroll
        for (int mi = 0; mi < 2; ++mi)
          #pragma unroll
          for (int e = 0; e < 4; ++e){
            int row = wm*32 + mi*16 + quad*4 + e;
            sred[(row*2 + 0)*2 + wn] = p0[mi][e];
            sred[(row*2 + 1)*2 + wn] = p1[mi][e];
          }
      }
      __syncthreads();
      if (tid < 128){
        int row = tid >> 1, j = tid & 1;
        float sv = (sred[(row*2 + j)*2 + 0] + sred[(row*2 + j)*2 + 1]) * 0.08838834764831845f;
        bool valid = (i0 + row) < NROWS;
        float ev = valid ? __expf(sv) : 0.f;
        Ef[row*2 + j] = ev;
        if (valid) Aout[(i0 + row)*2 + j] = ev;
        float t2 = ev;
        #pragma unroll
        for (int off = 2; off <= 32; off <<= 1) t2 += __shfl_xor(t2, off);
        if (lane < 2) gpartE[(size_t)blockIdx.x*4 + (tid >> 6)*2 + j] = t2;
      }
      __syncthreads();   // Ef visible; sred reads done before next Wb store
    } else {
      // ---- V epilogue: e-weighted column sums -> per-block gpart ----
      float e0[2][4], e1[2][4];
      #pragma unroll
      for (int mi = 0; mi < 2; ++mi)
        #pragma unroll
        for (int e = 0; e < 4; ++e){
          int row = wm*32 + mi*16 + quad*4 + e;
          e0[mi][e] = Ef[row*2 + 0];
          e1[mi][e] = Ef[row*2 + 1];
        }
      #pragma unroll
      for (int ni = 0; ni < 4; ++ni){
        int colv = (nt2 - 1)*128 + wn*64 + ni*16 + l16;
        float bvv = bv[colv];
        float b0 = 0.f, b1 = 0.f;
        #pragma unroll
        for (int mi = 0; mi < 2; ++mi)
          #pragma unroll
          for (int e = 0; e < 4; ++e){
            float v = acc[mi][ni][e] + bvv;
            b0 += v * e0[mi][e];
            b1 += v * e1[mi][e];
          }
        b0 += __shfl_xor(b0, 16); b0 += __shfl_xor(b0, 32);
        b1 += __shfl_xor(b1, 16); b1 += __shfl_xor(b1, 32);
        if (quad == 0){
          gpart[((size_t)blockIdx.x*2 + wm)*1024 + colv]       = b0;
          gpart[((size_t)blockIdx.x*2 + wm)*1024 + 512 + colv] = b1;
        }
      }
    }
  }
}

// ---------- k_red: parallel reduce -> sumEV[1024], sumE[2] ----------
__global__ void k_red(const float* __restrict__ gpart, const float* __restrict__ gpartE,
                      float* __restrict__ sumEV, float* __restrict__ sumE){
  const int t = threadIdx.x;
  if (blockIdx.x == 256){
    __shared__ float r0[256], r1[256];
    float s0 = 0.f, s1 = 0.f;
    for (int i = t; i < NB*2; i += 256){ s0 += gpartE[(size_t)i*2]; s1 += gpartE[(size_t)i*2 + 1]; }
    r0[t] = s0; r1[t] = s1;
    __syncthreads();
    for (int st = 128; st; st >>= 1){
      if (t < st){ r0[t] += r0[t + st]; r1[t] += r1[t + st]; }
      __syncthreads();
    }
    if (t == 0){ sumE[0] = r0[0]; sumE[1] = r1[0]; }
    return;
  }
  __shared__ float4 red[256];
  int col4 = blockIdx.x * 4;
  float4 s = {0.f, 0.f, 0.f, 0.f};
  for (int r = t; r < NB*2; r += 256){
    float4 v = *(const float4*)(gpart + (size_t)r*1024 + col4);
    s.x += v.x; s.y += v.y; s.z += v.z; s.w += v.w;
  }
  red[t] = s;
  __syncthreads();
  for (int st = 128; st; st >>= 1){
    if (t < st){
      float4 o = red[t + st];
      red[t].x += o.x; red[t].y += o.y; red[t].z += o.z; red[t].w += o.w;
    }
    __syncthreads();
  }
  if (t == 0) *(float4*)(sumEV + col4) = red[0];
}

// ---------- k_post: normalize A; compute B and Cout ----------
__global__ void k_post(float* __restrict__ out, const float* __restrict__ sumE,
                       const float* __restrict__ sumEV, const float* __restrict__ Wfcc,
                       const float* __restrict__ bfcc){
  if (blockIdx.x < 782){
    int idx = blockIdx.x*256 + threadIdx.x;
    if (idx < 200000) out[2 + idx] = out[2 + idx] / sumE[idx & 1];
    return;
  }
  __shared__ float red[512];
  int t = threadIdx.x;
  float z0 = sumE[0], z1 = sumE[1];
  float c0 = 0.f, c1 = 0.f;
  for (int e = t; e < 1024; e += 256){
    float bvv = sumEV[e] / ((e >> 9) ? z1 : z0);
    out[200002 + e] = bvv;
    c0 += bvv * Wfcc[e];
    c1 += bvv * Wfcc[1024 + e];
  }
  red[t] = c0; red[256 + t] = c1;
  __syncthreads();
  for (int s = 128; s; s >>= 1){
    if (t < s){ red[t] += red[t + s]; red[256 + t] += red[256 + t + s]; }
    __syncthreads();
  }
  if (t == 0){ out[0] = red[0] + bfcc[0]; out[1] = red[256] + bfcc[1]; }
}

// ---------- launch ----------
extern "C" void kernel_launch(void* const* d_in, const int* in_sizes, int n_in,
                              void* d_out, int out_size, void* d_ws, size_t ws_size,
                              hipStream_t stream){
  (void)in_sizes; (void)n_in; (void)out_size; (void)ws_size;
  const float* feats = (const float*)d_in[0];
  const float* c     = (const float*)d_in[1];
  const float* preds = (const float*)d_in[2];
  const float* W_lin = (const float*)d_in[3];
  const float* b_lin = (const float*)d_in[4];
  const float* W_q   = (const float*)d_in[5];
  const float* b_q   = (const float*)d_in[6];
  const float* W_v   = (const float*)d_in[7];
  const float* b_v   = (const float*)d_in[8];
  const float* W_fcc = (const float*)d_in[9];
  const float* b_fcc = (const float*)d_in[10];
  float* out = (float*)d_out;
  char* ws = (char*)d_ws;

  // ws layout (bytes) — every region fully rewritten each call
  u16*   wl_bf  = (u16*)(ws + 0);            // 524288
  u16*   wvq_bf = (u16*)(ws + 524288);       // 655360   -> 1179648
  Scal*  sc     = (Scal*)(ws + 1179648);     // 64       -> 1179712
  float* qmv    = (float*)(ws + 1179712);    // 1024     -> 1180736
  float* sumE   = (float*)(ws + 1180736);    // 64       -> 1180800
  float* sumEV  = (float*)(ws + 1180800);    // 4096     -> 1184896
  float* gpartE = (float*)(ws + 1184896);    // 1563*4*4 = 25008 (pad 25088) -> 1209984
  float* gpart  = (float*)(ws + 1209984);    // 1563*2*1024*4 = 12804096 -> 14014080
  // prep-phase scratch OVERLAYS gpart (gpart is written only later, by k_fused)
  uint32_t* hist = (uint32_t*)(ws + 1209984);          // 65536*4 = 262144
  ull*      cmax = (ull*)(ws + 1209984 + 262144);      // 16

  k_conv <<<2304, 256, 0, stream>>>(W_lin, W_v, W_q, wl_bf, wvq_bf, hist, cmax);
  k_sel1 <<<256, 256, 0, stream>>>(preds, c, hist, cmax);
  k_prep2<<<1, 1024, 0, stream>>>(preds, feats, W_lin, b_lin, W_q, b_q, hist, cmax, sc, qmv);
  k_fused<<<NB, 256, 0, stream>>>(feats, preds, wl_bf, wvq_bf, b_lin, b_v, b_q,
                                  qmv, sc, gpart, gpartE, out + 2);
  k_red  <<<257, 256, 0, stream>>>(gpart, gpartE, sumEV, sumE);
  k_post <<<783, 256, 0, stream>>>(out, sumE, sumEV, W_fcc, b_fcc);
}

// Round 2
// 632.952 us; speedup vs baseline: 1.2439x; 1.1570x over previous
//
#include <hip/hip_runtime.h>
#include <stdint.h>

typedef unsigned short u16;
typedef __bf16 bf16t;
typedef bf16t bf16x8 __attribute__((ext_vector_type(8)));
typedef float f32x4 __attribute__((ext_vector_type(4)));
typedef unsigned long long ull;

#define NROWS 100000
#define DD 512
#define QD 128
#define KSEL 20000
#define NB 1563   // ceil(100000/64)

// ---------- helpers ----------
__device__ __forceinline__ uint32_t fmono(float x){
  uint32_t u = __float_as_uint(x);
  return (u & 0x80000000u) ? ~u : (u | 0x80000000u);
}
__device__ __forceinline__ float finv(uint32_t k){  // inverse of fmono
  uint32_t u = (k & 0x80000000u) ? (k & 0x7fffffffu) : ~k;
  return __uint_as_float(u);
}
__device__ __forceinline__ u16 f2bf(float x){  // RNE float->bf16 bits
  uint32_t u = __float_as_uint(x);
  u += 0x7fffu + ((u >> 16) & 1u);
  return (u16)(u >> 16);
}
__device__ __forceinline__ uint32_t pkbf(float a, float b){
  return (uint32_t)f2bf(a) | ((uint32_t)f2bf(b) << 16);
}

struct Scal {
  uint32_t keyT;
  float Z;
  uint32_t pad[14];
};

#define MFMA16(A,B,C) __builtin_amdgcn_mfma_f32_16x16x32_bf16(A,B,C,0,0,0)

// ---------- k_conv: fp32 weights -> bf16 chunk-format; zero hist / cmax ----------
// Chunk ci (0..143) = 128 output-rows x 32 K-cols, stored contiguously (4096 u16)
// in the exact per-thread order k_fused stages it: elem = ci*4096 + r*32 + col.
__global__ void k_conv(const float* __restrict__ Wl, const float* __restrict__ Wv,
                       const float* __restrict__ Wq, u16* __restrict__ wch,
                       uint32_t* __restrict__ hist, ull* __restrict__ cmax){
  int idx = blockIdx.x*256 + threadIdx.x;          // grid 2304*256 = 589824 exactly
  if (idx < 65536) hist[idx] = 0u;
  if (idx == 0){ cmax[0] = 0ull; cmax[1] = 0ull; }
  int ci  = idx >> 12;
  int rem = idx & 4095;
  int r   = rem >> 5;
  int col = rem & 31;
  float v;
  if (ci < 64){
    int nt = ci >> 4, kc = ci & 15;
    v = Wl[(size_t)(nt*128 + r)*DD + kc*32 + col];
  } else {
    int c2 = ci - 64;
    int nt2 = c2 >> 4, kc = c2 & 15;
    if (nt2 == 0) v = Wq[(size_t)r*DD + kc*32 + col];
    else          v = Wv[(size_t)((nt2-1)*128 + r)*DD + kc*32 + col];
  }
  wch[idx] = f2bf(v);
}

// ---------- k_sel1: multi-block 16-bit histogram of fmono(preds) + c-argmax partials ----------
__global__ void k_sel1(const float* __restrict__ preds, const float* __restrict__ c,
                       uint32_t* __restrict__ hist, ull* __restrict__ cmax){
  __shared__ ull kr0[4], kr1[4];
  const int t = threadIdx.x;                // 256
  const int gid = blockIdx.x*256 + t;       // grid 256 blocks -> 65536 threads
  const int lane = t & 63;

  const float4* p4 = (const float4*)preds;
  for (int i = gid; i < 25000; i += 65536){
    float4 v = p4[i];
    atomicAdd(&hist[fmono(v.x) >> 16], 1u);
    atomicAdd(&hist[fmono(v.y) >> 16], 1u);
    atomicAdd(&hist[fmono(v.z) >> 16], 1u);
    atomicAdd(&hist[fmono(v.w) >> 16], 1u);
  }

  ull k0 = 0ull, k1 = 0ull;
  const float4* c4 = (const float4*)c;
  for (int i = gid; i < 50000; i += 65536){
    float4 v = c4[i];                       // rows 2i (x=c0,y=c1), 2i+1 (z=c0,w=c1)
    uint32_t r0 = 2u*i, r1 = 2u*i + 1u;
    ull a0 = ((ull)fmono(v.x) << 32) | (ull)(~r0);
    ull a1 = ((ull)fmono(v.z) << 32) | (ull)(~r1);
    ull b0 = ((ull)fmono(v.y) << 32) | (ull)(~r0);
    ull b1 = ((ull)fmono(v.w) << 32) | (ull)(~r1);
    if (a0 > k0) k0 = a0;
    if (a1 > k0) k0 = a1;
    if (b0 > k1) k1 = b0;
    if (b1 > k1) k1 = b1;
  }
  #pragma unroll
  for (int off = 32; off; off >>= 1){
    ull o0 = __shfl_xor(k0, off); if (o0 > k0) k0 = o0;
    ull o1 = __shfl_xor(k1, off); if (o1 > k1) k1 = o1;
  }
  if (lane == 0){ kr0[t >> 6] = k0; kr1[t >> 6] = k1; }
  __syncthreads();
  if (t == 0){
    ull m0 = kr0[0], m1 = kr1[0];
    #pragma unroll
    for (int w = 1; w < 4; ++w){
      if (kr0[w] > m0) m0 = kr0[w];
      if (kr1[w] > m1) m1 = kr1[w];
    }
    atomicMax(&cmax[0], m0);
    atomicMax(&cmax[1], m1);
  }
}

// ---------- k_prep2: one block — scan hist, exact keyT, Z, m_feats, q_max ----------
#define CAND_CAP 8192
__launch_bounds__(1024)
__global__ void k_prep2(const float* __restrict__ preds, const float* __restrict__ feats,
                        const float* __restrict__ Wl, const float* __restrict__ bl,
                        const float* __restrict__ Wq, const float* __restrict__ bq,
                        const uint32_t* __restrict__ hist, const ull* __restrict__ cmax,
                        Scal* __restrict__ sc, float* __restrict__ qmv){
  __shared__ uint32_t cand[CAND_CAP];
  __shared__ uint32_t wsum[16], woff[16];
  __shared__ float zred[16];
  __shared__ uint32_t s_B, s_cumBelow, s_keyT, candN;
  __shared__ float s_Z;
  __shared__ uint32_t s_mi[2];
  __shared__ float fmX[2][512];
  __shared__ float fmF[2][512];
  const int t = threadIdx.x;
  const int lane = t & 63, wv = t >> 6;

  if (t == 0){
    candN = 0;
    s_mi[0] = ~(uint32_t)(cmax[0] & 0xffffffffull);
    s_mi[1] = ~(uint32_t)(cmax[1] & 0xffffffffull);
  }

  // ---- parallel scan of 65536-bin histogram; find bucket containing rank KSEL ----
  const int b0 = t*64;
  uint32_t local = 0;
  {
    const uint4* h4 = (const uint4*)(hist + b0);
    #pragma unroll 4
    for (int q = 0; q < 16; ++q){ uint4 hv = h4[q]; local += hv.x + hv.y + hv.z + hv.w; }
  }
  uint32_t x = local;
  #pragma unroll
  for (int off = 1; off < 64; off <<= 1){
    uint32_t y = __shfl_up(x, off);
    if (lane >= off) x += y;
  }
  if (lane == 63) wsum[wv] = x;
  __syncthreads();
  if (t == 0){
    uint32_t cum = 0;
    for (int w = 0; w < 16; ++w){ woff[w] = cum; cum += wsum[w]; }
  }
  __syncthreads();
  uint32_t excl = x - local + woff[wv];       // exclusive prefix of this thread's 64 bins
  if (excl < KSEL && excl + local >= KSEL){   // unique crossing thread
    uint32_t cum = excl;
    for (int b = 0; b < 64; ++b){
      uint32_t h = hist[b0 + b];
      if (cum + h >= KSEL){ s_B = (uint32_t)(b0 + b); s_cumBelow = cum; break; }
      cum += h;
    }
  }
  __syncthreads();
  const uint32_t B = s_B;

  // ---- one pass over preds: sum exp over buckets > B; collect bucket-B candidates ----
  float sA = 0.f;
  const float4* p4 = (const float4*)preds;
  for (int i = t; i < 25000; i += 1024){
    float4 v = p4[i];
    float vv[4] = {v.x, v.y, v.z, v.w};
    #pragma unroll
    for (int e = 0; e < 4; ++e){
      uint32_t k = fmono(vv[e]);
      uint32_t bb = k >> 16;
      if (bb > B){
        sA += __expf(vv[e]);
      } else if (bb == B){
        uint32_t idx = atomicAdd(&candN, 1u);
        if (idx < CAND_CAP) cand[idx] = k;
      }
    }
  }
  #pragma unroll
  for (int off = 32; off; off >>= 1) sA += __shfl_xor(sA, off);
  if (lane == 0) zred[wv] = sA;
  __syncthreads();

  // ---- exact rank select among candidates (O(n^2), n ~ few hundred) ----
  const uint32_t n = candN < CAND_CAP ? candN : CAND_CAP;
  const uint32_t r = KSEL - s_cumBelow;       // 1-indexed rank within bucket
  for (uint32_t i = t; i < n; i += 1024){
    uint32_t ki = cand[i];
    uint32_t less = 0, eq = 0;
    for (uint32_t j = 0; j < n; ++j){
      uint32_t kj = cand[j];
      less += (kj < ki) ? 1u : 0u;
      eq   += (kj == ki) ? 1u : 0u;
    }
    if (less < r && r <= less + eq) s_keyT = ki;
  }
  __syncthreads();
  const uint32_t keyT = s_keyT;

  // ---- add exp of candidates strictly above keyT ----
  float sCA = 0.f;
  for (uint32_t i = t; i < n; i += 1024){
    uint32_t k = cand[i];
    if (k > keyT) sCA += __expf(finv(k));
  }
  #pragma unroll
  for (int off = 32; off; off >>= 1) sCA += __shfl_xor(sCA, off);
  if (lane == 0) zred[wv] += sCA;
  __syncthreads();
  if (t == 0){
    float Z = (float)KSEL;                    // exp(0)=1 for each of the KSEL zeroed entries
    for (int w = 0; w < 16; ++w) Z += zred[w];
    s_Z = Z;
    sc->keyT = keyT; sc->Z = Z;
  }
  __syncthreads();

  // ---- load the 2 argmax feats rows ----
  {
    int j = t >> 9, col = t & 511;
    fmX[j][col] = feats[(size_t)s_mi[j]*DD + col];
  }
  __syncthreads();

  // ---- exact fp32 m_feats ----
  {
    int nn = t >> 1, h = t & 1;
    const float4* wr4 = (const float4*)(Wl + (size_t)nn*DD + h*256);
    const float4* x04 = (const float4*)(&fmX[0][h*256]);
    const float4* x14 = (const float4*)(&fmX[1][h*256]);
    float a0 = 0.f, a1 = 0.f;
    #pragma unroll 4
    for (int k = 0; k < 64; ++k){
      float4 w = wr4[k], u = x04[k], v = x14[k];
      a0 += u.x*w.x + u.y*w.y + u.z*w.z + u.w*w.w;
      a1 += v.x*w.x + v.y*w.y + v.z*w.z + v.w*w.w;
    }
    a0 += __shfl_xor(a0, 1);
    a1 += __shfl_xor(a1, 1);
    if (h == 0){
      float Z = s_Z;
      float p0 = preds[s_mi[0]]; float q0 = (fmono(p0) <= keyT) ? 0.f : p0;
      float g0 = 1.f + __expf(q0) / Z;
      float p1 = preds[s_mi[1]]; float q1 = (fmono(p1) <= keyT) ? 0.f : p1;
      float g1 = 1.f + __expf(q1) / Z;
      float v0 = bl[nn] + g0*a0; fmF[0][nn] = v0 > 0.f ? v0 : 0.f;
      float v1 = bl[nn] + g1*a1; fmF[1][nn] = v1 > 0.f ? v1 : 0.f;
    }
  }
  __syncthreads();

  // ---- q_max ----
  if (t < 256){
    int q = t & 127, j = t >> 7;
    const float4* wr4 = (const float4*)(Wq + (size_t)q*DD);
    const float4* x4  = (const float4*)(fmF[j]);
    float a0 = 0.f, a1 = 0.f;
    #pragma unroll 4
    for (int k = 0; k < 128; k += 2){
      float4 w0 = wr4[k], u0 = x4[k];
      float4 w1 = wr4[k+1], u1 = x4[k+1];
      a0 += u0.x*w0.x + u0.y*w0.y + u0.z*w0.z + u0.w*w0.w;
      a1 += u1.x*w1.x + u1.y*w1.y + u1.z*w1.z + u1.w*w1.w;
    }
    qmv[j*QD + q] = tanhf(bq[q] + a0 + a1);
  }
}

// ---------- k_fused v2: M=64, 2x2 wave grid; double-buffered Wb, 1 barrier/step,
// 2-deep chunk prefetch, XOR-swizzled pad-free LDS. LDS = 81920 B exactly (2 blocks/CU).
// AF [64][512] u16 swizzled (blk^ = row&7 on 16B blocks); WB0/WB1 [128][32] u16 (blk^ = row&3).
__launch_bounds__(256, 2)
__global__ void k_fused(const float* __restrict__ feats, const float* __restrict__ preds,
                        const u16* __restrict__ wch,
                        const float* __restrict__ bl, const float* __restrict__ bv,
                        const float* __restrict__ bq, const float* __restrict__ qmv,
                        const Scal* __restrict__ sc,
                        float* __restrict__ gpart, float* __restrict__ gpartE,
                        float* __restrict__ Aout){
  __shared__ __align__(16) u16 lds[40960];   // 81920 B
  u16* AF  = lds;                 // [64][512]
  u16* WB0 = lds + 32768;         // [128][32]
  u16* WB1 = lds + 36864;         // [128][32]
  float* sred = (float*)WB1;      // transient overlay during Q epilogue (WB1 dead there)
  const int tid = threadIdx.x;
  const int lane = tid & 63, quad = lane >> 4, l16 = lane & 15;
  const int wave = tid >> 6, wm = wave >> 1, wn = wave & 1;
  const long i0 = (long)blockIdx.x * 64;
  const uint32_t keyT = sc->keyT;
  const float Z = sc->Z;

  // ---- stage gX tile (64 x 512) into AF as bf16, g folded; row = lane; swizzled ----
  {
    int row = lane;
    long ir = i0 + row; if (ir >= NROWS) ir = NROWS - 1;
    float p = preds[ir];
    float pm = (fmono(p) <= keyT) ? 0.f : p;
    float g = 1.f + __expf(pm) / Z;
    const float4* src = (const float4*)(feats + ir*DD + wave*128);
    u16* dstrow = AF + row*512;
    const int swz = row & 7;
    #pragma unroll
    for (int j = 0; j < 16; ++j){
      float4 a = src[2*j], b = src[2*j + 1];
      uint4 pk;
      pk.x = pkbf(a.x*g, a.y*g); pk.y = pkbf(a.z*g, a.w*g);
      pk.z = pkbf(b.x*g, b.y*g); pk.w = pkbf(b.z*g, b.w*g);
      int blk = (wave << 4) | j;
      *(uint4*)&dstrow[(blk ^ swz) << 3] = pk;
    }
  }

  // ---- weight pipeline prologue: chunk0 -> WB0; chunk1 in pB; chunk2 in pA ----
  const u16* wsrc = wch + (size_t)tid * 16;   // thread's 32B slice; chunk stride 4096 u16
  const int rS = tid >> 1, pS = tid & 1;
  const int offA = rS*32 + ((((pS << 1)    ) ^ (rS & 3)) << 3);
  const int offB = rS*32 + ((((pS << 1) | 1) ^ (rS & 3)) << 3);
  uint4 pA0 = *(const uint4*)(wsrc);
  uint4 pA1 = *(const uint4*)(wsrc + 8);
  uint4 pB0 = *(const uint4*)(wsrc + 4096);
  uint4 pB1 = *(const uint4*)(wsrc + 4096 + 8);
  *(uint4*)&WB0[offA] = pA0;
  *(uint4*)&WB0[offB] = pA1;
  pA0 = *(const uint4*)(wsrc + 8192);
  pA1 = *(const uint4*)(wsrc + 8192 + 8);
  __syncthreads();   // AF staged, WB0 = chunk0

  // ---- precomputed read offsets ----
  const int sb  = l16 & 7;                      // A-row swizzle bits
  const int sb2 = l16 & 3;                      // B-row swizzle bits
  const int base_a = (wm*32 + l16) * 512;       // a1 = base_a + 8192
  const int rB = wn*64 + l16;
  const int qsw = (quad ^ sb2) << 3;
  const int off_b0 = (rB +  0)*32 + qsw;
  const int off_b1 = (rB + 16)*32 + qsw;
  const int off_b2 = (rB + 32)*32 + qsw;
  const int off_b3 = (rB + 48)*32 + qsw;

  f32x4 acc[2][4];
  uint32_t pkF[4][16];
  float eR0[2][4], eR1[2][4];
  int ci = 0;

#define KSTEP(BUFC, BUFN, P0, P1)                                                  \
  {                                                                                \
    int abk = (((ci & 15) << 2) | quad) ^ sb;                                      \
    bf16x8 a0 = *(const bf16x8*)&AF[base_a + (abk << 3)];                          \
    bf16x8 a1 = *(const bf16x8*)&AF[base_a + 8192 + (abk << 3)];                   \
    bf16x8 b0 = *(const bf16x8*)&BUFC[off_b0];                                     \
    bf16x8 b1 = *(const bf16x8*)&BUFC[off_b1];                                     \
    bf16x8 b2 = *(const bf16x8*)&BUFC[off_b2];                                     \
    bf16x8 b3 = *(const bf16x8*)&BUFC[off_b3];                                     \
    if (ci + 1 < 144){ *(uint4*)&BUFN[offA] = P0; *(uint4*)&BUFN[offB] = P1; }     \
    if (ci + 3 < 144){                                                             \
      const u16* s_ = wsrc + (size_t)(ci + 3)*4096;                                \
      P0 = *(const uint4*)s_; P1 = *(const uint4*)(s_ + 8);                        \
    }                                                                              \
    acc[0][0] = MFMA16(a0, b0, acc[0][0]);                                         \
    acc[0][1] = MFMA16(a0, b1, acc[0][1]);                                         \
    acc[0][2] = MFMA16(a0, b2, acc[0][2]);                                         \
    acc[0][3] = MFMA16(a0, b3, acc[0][3]);                                         \
    acc[1][0] = MFMA16(a1, b0, acc[1][0]);                                         \
    acc[1][1] = MFMA16(a1, b1, acc[1][1]);                                         \
    acc[1][2] = MFMA16(a1, b2, acc[1][2]);                                         \
    acc[1][3] = MFMA16(a1, b3, acc[1][3]);                                         \
    __syncthreads();                                                               \
    ++ci;                                                                          \
  }

  // ---- stage 1: f = relu(gX @ Wl^T + bl) -> pkF registers ----
  for (int nt = 0; nt < 4; ++nt){
    #pragma unroll
    for (int mi = 0; mi < 2; ++mi)
      #pragma unroll
      for (int ni = 0; ni < 4; ++ni) acc[mi][ni] = (f32x4){0.f,0.f,0.f,0.f};
    for (int kh = 0; kh < 8; ++kh){
      KSTEP(WB0, WB1, pB0, pB1);   // ci even
      KSTEP(WB1, WB0, pA0, pA1);   // ci odd
    }
    #pragma unroll
    for (int ni = 0; ni < 4; ++ni){
      float bb = bl[nt*128 + wn*64 + ni*16 + l16];
      #pragma unroll
      for (int mi = 0; mi < 2; ++mi){
        float e0 = acc[mi][ni][0] + bb; e0 = e0 > 0.f ? e0 : 0.f;
        float e1 = acc[mi][ni][1] + bb; e1 = e1 > 0.f ? e1 : 0.f;
        float e2 = acc[mi][ni][2] + bb; e2 = e2 > 0.f ? e2 : 0.f;
        float e3 = acc[mi][ni][3] + bb; e3 = e3 > 0.f ? e3 : 0.f;
        pkF[nt][mi*8 + ni*2 + 0] = pkbf(e0, e1);
        pkF[nt][mi*8 + ni*2 + 1] = pkbf(e2, e3);
      }
    }
  }

  // ---- transpose pkF (C-layout) -> F tile in AF (A-operand layout, swizzled) ----
  // last KSTEP's barrier guarantees all stage-1 AF reads are done
  #pragma unroll
  for (int nt = 0; nt < 4; ++nt)
    #pragma unroll
    for (int ni = 0; ni < 4; ++ni)
      #pragma unroll
      for (int mi = 0; mi < 2; ++mi){
        int col = nt*128 + wn*64 + ni*16 + l16;
        int r0 = wm*32 + mi*16 + quad*4;
        uint32_t x = pkF[nt][mi*8 + ni*2], y = pkF[nt][mi*8 + ni*2 + 1];
        int cb = col >> 3, cw = col & 7;
        AF[(r0+0)*512 + (((cb) ^ ((r0+0)&7)) << 3) + cw] = (u16)x;
        AF[(r0+1)*512 + (((cb) ^ ((r0+1)&7)) << 3) + cw] = (u16)(x >> 16);
        AF[(r0+2)*512 + (((cb) ^ ((r0+2)&7)) << 3) + cw] = (u16)y;
        AF[(r0+3)*512 + (((cb) ^ ((r0+3)&7)) << 3) + cw] = (u16)(y >> 16);
      }
  __syncthreads();   // F tile visible before stage-2 reads

  // ---- stage 2: [Q|V] = f @ W^T ; Q first (nt2=0 -> e), then V weighted ----
  for (int nt2 = 0; nt2 < 5; ++nt2){
    #pragma unroll
    for (int mi = 0; mi < 2; ++mi)
      #pragma unroll
      for (int ni = 0; ni < 4; ++ni) acc[mi][ni] = (f32x4){0.f,0.f,0.f,0.f};
    for (int kh = 0; kh < 8; ++kh){
      KSTEP(WB0, WB1, pB0, pB1);
      KSTEP(WB1, WB0, pA0, pA1);
    }
    if (nt2 == 0){
      // ---- Q epilogue: tanh, dot with qmv, e = exp(score/sqrt(128)) ----
      float p0[2][4], p1[2][4];
      #pragma unroll
      for (int mi = 0; mi < 2; ++mi)
        #pragma unroll
        for (int e = 0; e < 4; ++e){ p0[mi][e] = 0.f; p1[mi][e] = 0.f; }
      #pragma unroll
      for (int ni = 0; ni < 4; ++ni){
        int qc = wn*64 + ni*16 + l16;
        float bqv = bq[qc], q0 = qmv[qc], q1 = qmv[QD + qc];
        #pragma unroll
        for (int mi = 0; mi < 2; ++mi)
          #pragma unroll
          for (int e = 0; e < 4; ++e){
            float tq = tanhf(acc[mi][ni][e] + bqv);
            p0[mi][e] += tq * q0;
            p1[mi][e] += tq * q1;
          }
      }
      #pragma unroll
      for (int off = 1; off <= 8; off <<= 1)
        #pragma unroll
        for (int mi = 0; mi < 2; ++mi)
          #pragma unroll
          for (int e = 0; e < 4; ++e){
            p0[mi][e] += __shfl_xor(p0[mi][e], off);
            p1[mi][e] += __shfl_xor(p1[mi][e], off);
          }
      // WB1 holds dead chunk (79); safe to overlay sred until next step's store
      if (l16 == 0){
        #pragma unroll
        for (int mi = 0; mi < 2; ++mi)
          #pragma unroll
          for (int e = 0; e < 4; ++e){
            int row = wm*32 + mi*16 + quad*4 + e;
            sred[(row*2 + 0)*2 + wn] = p0[mi][e];
            sred[(row*2 + 1)*2 + wn] = p1[mi][e];
          }
      }
      __syncthreads();   // sred visible
      // every thread derives its own e-values into registers
      #pragma unroll
      for (int mi = 0; mi < 2; ++mi)
        #pragma unroll
        for (int e = 0; e < 4; ++e){
          int row = wm*32 + mi*16 + quad*4 + e;
          bool valid = (i0 + row) < NROWS;
          float sv0 = (sred[(row*2 + 0)*2 + 0] + sred[(row*2 + 0)*2 + 1]) * 0.08838834764831845f;
          float sv1 = (sred[(row*2 + 1)*2 + 0] + sred[(row*2 + 1)*2 + 1]) * 0.08838834764831845f;
          eR0[mi][e] = valid ? __expf(sv0) : 0.f;
          eR1[mi][e] = valid ? __expf(sv1) : 0.f;
        }
      if (tid < 128){
        int row = tid >> 1, j = tid & 1;
        float sv = (sred[(row*2 + j)*2 + 0] + sred[(row*2 + j)*2 + 1]) * 0.08838834764831845f;
        bool valid = (i0 + row) < NROWS;
        float ev = valid ? __expf(sv) : 0.f;
        if (valid) Aout[(i0 + row)*2 + j] = ev;
        float t2 = ev;
        #pragma unroll
        for (int off = 2; off <= 32; off <<= 1) t2 += __shfl_xor(t2, off);
        if (lane < 2) gpartE[(size_t)blockIdx.x*4 + (tid >> 6)*2 + j] = t2;
      }
      __syncthreads();   // sred reads done before next step overwrites WB1
    } else {
      // ---- V epilogue: e-weighted column sums -> per-block gpart ----
      #pragma unroll
      for (int ni = 0; ni < 4; ++ni){
        int colv = (nt2 - 1)*128 + wn*64 + ni*16 + l16;
        float bvv = bv[colv];
        float b0 = 0.f, b1 = 0.f;
        #pragma unroll
        for (int mi = 0; mi < 2; ++mi)
          #pragma unroll
          for (int e = 0; e < 4; ++e){
            float v = acc[mi][ni][e] + bvv;
            b0 += v * eR0[mi][e];
            b1 += v * eR1[mi][e];
          }
        b0 += __shfl_xor(b0, 16); b0 += __shfl_xor(b0, 32);
        b1 += __shfl_xor(b1, 16); b1 += __shfl_xor(b1, 32);
        if (quad == 0){
          gpart[((size_t)blockIdx.x*2 + wm)*1024 + colv]       = b0;
          gpart[((size_t)blockIdx.x*2 + wm)*1024 + 512 + colv] = b1;
        }
      }
    }
  }
#undef KSTEP
}

// ---------- k_red: parallel reduce -> sumEV[1024], sumE[2] ----------
__global__ void k_red(const float* __restrict__ gpart, const float* __restrict__ gpartE,
                      float* __restrict__ sumEV, float* __restrict__ sumE){
  const int t = threadIdx.x;
  if (blockIdx.x == 256){
    __shared__ float r0[256], r1[256];
    float s0 = 0.f, s1 = 0.f;
    for (int i = t; i < NB*2; i += 256){ s0 += gpartE[(size_t)i*2]; s1 += gpartE[(size_t)i*2 + 1]; }
    r0[t] = s0; r1[t] = s1;
    __syncthreads();
    for (int st = 128; st; st >>= 1){
      if (t < st){ r0[t] += r0[t + st]; r1[t] += r1[t + st]; }
      __syncthreads();
    }
    if (t == 0){ sumE[0] = r0[0]; sumE[1] = r1[0]; }
    return;
  }
  __shared__ float4 red[256];
  int col4 = blockIdx.x * 4;
  float4 s = {0.f, 0.f, 0.f, 0.f};
  for (int r = t; r < NB*2; r += 256){
    float4 v = *(const float4*)(gpart + (size_t)r*1024 + col4);
    s.x += v.x; s.y += v.y; s.z += v.z; s.w += v.w;
  }
  red[t] = s;
  __syncthreads();
  for (int st = 128; st; st >>= 1){
    if (t < st){
      float4 o = red[t + st];
      red[t].x += o.x; red[t].y += o.y; red[t].z += o.z; red[t].w += o.w;
    }
    __syncthreads();
  }
  if (t == 0) *(float4*)(sumEV + col4) = red[0];
}

// ---------- k_post: normalize A; compute B and Cout ----------
__global__ void k_post(float* __restrict__ out, const float* __restrict__ sumE,
                       const float* __restrict__ sumEV, const float* __restrict__ Wfcc,
                       const float* __restrict__ bfcc){
  if (blockIdx.x < 782){
    int idx = blockIdx.x*256 + threadIdx.x;
    if (idx < 200000) out[2 + idx] = out[2 + idx] / sumE[idx & 1];
    return;
  }
  __shared__ float red[512];
  int t = threadIdx.x;
  float z0 = sumE[0], z1 = sumE[1];
  float c0 = 0.f, c1 = 0.f;
  for (int e = t; e < 1024; e += 256){
    float bvv = sumEV[e] / ((e >> 9) ? z1 : z0);
    out[200002 + e] = bvv;
    c0 += bvv * Wfcc[e];
    c1 += bvv * Wfcc[1024 + e];
  }
  red[t] = c0; red[256 + t] = c1;
  __syncthreads();
  for (int s = 128; s; s >>= 1){
    if (t < s){ red[t] += red[t + s]; red[256 + t] += red[256 + t + s]; }
    __syncthreads();
  }
  if (t == 0){ out[0] = red[0] + bfcc[0]; out[1] = red[256] + bfcc[1]; }
}

// ---------- launch ----------
extern "C" void kernel_launch(void* const* d_in, const int* in_sizes, int n_in,
                              void* d_out, int out_size, void* d_ws, size_t ws_size,
                              hipStream_t stream){
  (void)in_sizes; (void)n_in; (void)out_size; (void)ws_size;
  const float* feats = (const float*)d_in[0];
  const float* c     = (const float*)d_in[1];
  const float* preds = (const float*)d_in[2];
  const float* W_lin = (const float*)d_in[3];
  const float* b_lin = (const float*)d_in[4];
  const float* W_q   = (const float*)d_in[5];
  const float* b_q   = (const float*)d_in[6];
  const float* W_v   = (const float*)d_in[7];
  const float* b_v   = (const float*)d_in[8];
  const float* W_fcc = (const float*)d_in[9];
  const float* b_fcc = (const float*)d_in[10];
  float* out = (float*)d_out;
  char* ws = (char*)d_ws;

  // ws layout (bytes) — every region fully rewritten each call
  u16*   wch    = (u16*)(ws + 0);            // 1179648 (144 chunks x 8KB)
  Scal*  sc     = (Scal*)(ws + 1179648);     // 64       -> 1179712
  float* qmv    = (float*)(ws + 1179712);    // 1024     -> 1180736
  float* sumE   = (float*)(ws + 1180736);    // 64       -> 1180800
  float* sumEV  = (float*)(ws + 1180800);    // 4096     -> 1184896
  float* gpartE = (float*)(ws + 1184896);    // 1563*4*4 = 25008 (pad 25088) -> 1209984
  float* gpart  = (float*)(ws + 1209984);    // 1563*2*1024*4 = 12804096 -> 14014080
  // prep-phase scratch OVERLAYS gpart (gpart is written only later, by k_fused)
  uint32_t* hist = (uint32_t*)(ws + 1209984);          // 65536*4 = 262144
  ull*      cmax = (ull*)(ws + 1209984 + 262144);      // 16

  k_conv <<<2304, 256, 0, stream>>>(W_lin, W_v, W_q, wch, hist, cmax);
  k_sel1 <<<256, 256, 0, stream>>>(preds, c, hist, cmax);
  k_prep2<<<1, 1024, 0, stream>>>(preds, feats, W_lin, b_lin, W_q, b_q, hist, cmax, sc, qmv);
  k_fused<<<NB, 256, 0, stream>>>(feats, preds, wch, b_lin, b_v, b_q,
                                  qmv, sc, gpart, gpartE, out + 2);
  k_red  <<<257, 256, 0, stream>>>(gpart, gpartE, sumEV, sumE);
  k_post <<<783, 256, 0, stream>>>(out, sumE, sumEV, W_fcc, b_fcc);
}

// Round 3
// 603.643 us; speedup vs baseline: 1.3043x; 1.0486x over previous
//
#include <hip/hip_runtime.h>
#include <stdint.h>

typedef unsigned short u16;
typedef __bf16 bf16t;
typedef bf16t bf16x8 __attribute__((ext_vector_type(8)));
typedef float f32x4 __attribute__((ext_vector_type(4)));
typedef unsigned long long ull;

#define NROWS 100000
#define DD 512
#define QD 128
#define KSEL 20000
#define NB 1563   // ceil(100000/64)

// ---------- helpers ----------
__device__ __forceinline__ uint32_t fmono(float x){
  uint32_t u = __float_as_uint(x);
  return (u & 0x80000000u) ? ~u : (u | 0x80000000u);
}
__device__ __forceinline__ float finv(uint32_t k){  // inverse of fmono
  uint32_t u = (k & 0x80000000u) ? (k & 0x7fffffffu) : ~k;
  return __uint_as_float(u);
}
__device__ __forceinline__ u16 f2bf(float x){  // RNE float->bf16 bits
  uint32_t u = __float_as_uint(x);
  u += 0x7fffu + ((u >> 16) & 1u);
  return (u16)(u >> 16);
}
__device__ __forceinline__ uint32_t pkbf(float a, float b){
  return (uint32_t)f2bf(a) | ((uint32_t)f2bf(b) << 16);
}

struct Scal {
  uint32_t keyT;
  float Z;
  uint32_t pad[14];
};

#define MFMA16(A,B,C) __builtin_amdgcn_mfma_f32_16x16x32_bf16(A,B,C,0,0,0)

// ---------- k_conv: fp32 weights -> bf16 chunk-format; zero hist / cmax ----------
// Chunk ci (0..143) = 128 output-rows x 32 K-cols, contiguous (4096 u16):
// elem = ci*4096 + r*32 + col.  Stage1: ci = nt*16+kc (Wl). Stage2: 64 + nt2*16+kc (Wq then Wv).
__global__ void k_conv(const float* __restrict__ Wl, const float* __restrict__ Wv,
                       const float* __restrict__ Wq, u16* __restrict__ wch,
                       uint32_t* __restrict__ hist, ull* __restrict__ cmax){
  int idx = blockIdx.x*256 + threadIdx.x;          // grid 2304*256 = 589824 exactly
  if (idx < 65536) hist[idx] = 0u;
  if (idx == 0){ cmax[0] = 0ull; cmax[1] = 0ull; }
  int ci  = idx >> 12;
  int rem = idx & 4095;
  int r   = rem >> 5;
  int col = rem & 31;
  float v;
  if (ci < 64){
    int nt = ci >> 4, kc = ci & 15;
    v = Wl[(size_t)(nt*128 + r)*DD + kc*32 + col];
  } else {
    int c2 = ci - 64;
    int nt2 = c2 >> 4, kc = c2 & 15;
    if (nt2 == 0) v = Wq[(size_t)r*DD + kc*32 + col];
    else          v = Wv[(size_t)((nt2-1)*128 + r)*DD + kc*32 + col];
  }
  wch[idx] = f2bf(v);
}

// ---------- k_sel1: multi-block 16-bit histogram of fmono(preds) + c-argmax partials ----------
__global__ void k_sel1(const float* __restrict__ preds, const float* __restrict__ c,
                       uint32_t* __restrict__ hist, ull* __restrict__ cmax){
  __shared__ ull kr0[4], kr1[4];
  const int t = threadIdx.x;                // 256
  const int gid = blockIdx.x*256 + t;       // grid 256 blocks -> 65536 threads
  const int lane = t & 63;

  const float4* p4 = (const float4*)preds;
  for (int i = gid; i < 25000; i += 65536){
    float4 v = p4[i];
    atomicAdd(&hist[fmono(v.x) >> 16], 1u);
    atomicAdd(&hist[fmono(v.y) >> 16], 1u);
    atomicAdd(&hist[fmono(v.z) >> 16], 1u);
    atomicAdd(&hist[fmono(v.w) >> 16], 1u);
  }

  ull k0 = 0ull, k1 = 0ull;
  const float4* c4 = (const float4*)c;
  for (int i = gid; i < 50000; i += 65536){
    float4 v = c4[i];                       // rows 2i (x=c0,y=c1), 2i+1 (z=c0,w=c1)
    uint32_t r0 = 2u*i, r1 = 2u*i + 1u;
    ull a0 = ((ull)fmono(v.x) << 32) | (ull)(~r0);
    ull a1 = ((ull)fmono(v.z) << 32) | (ull)(~r1);
    ull b0 = ((ull)fmono(v.y) << 32) | (ull)(~r0);
    ull b1 = ((ull)fmono(v.w) << 32) | (ull)(~r1);
    if (a0 > k0) k0 = a0;
    if (a1 > k0) k0 = a1;
    if (b0 > k1) k1 = b0;
    if (b1 > k1) k1 = b1;
  }
  #pragma unroll
  for (int off = 32; off; off >>= 1){
    ull o0 = __shfl_xor(k0, off); if (o0 > k0) k0 = o0;
    ull o1 = __shfl_xor(k1, off); if (o1 > k1) k1 = o1;
  }
  if (lane == 0){ kr0[t >> 6] = k0; kr1[t >> 6] = k1; }
  __syncthreads();
  if (t == 0){
    ull m0 = kr0[0], m1 = kr1[0];
    #pragma unroll
    for (int w = 1; w < 4; ++w){
      if (kr0[w] > m0) m0 = kr0[w];
      if (kr1[w] > m1) m1 = kr1[w];
    }
    atomicMax(&cmax[0], m0);
    atomicMax(&cmax[1], m1);
  }
}

// ---------- k_prep2: one block — scan hist, exact keyT, Z ----------
#define CAND_CAP 8192
__launch_bounds__(1024)
__global__ void k_prep2(const float* __restrict__ preds,
                        const uint32_t* __restrict__ hist,
                        Scal* __restrict__ sc){
  __shared__ uint32_t cand[CAND_CAP];
  __shared__ uint32_t wsum[16], woff[16];
  __shared__ float zred[16];
  __shared__ uint32_t s_B, s_cumBelow, s_keyT, candN;
  const int t = threadIdx.x;
  const int lane = t & 63, wv = t >> 6;

  if (t == 0) candN = 0;

  // ---- parallel scan of 65536-bin histogram; find bucket containing rank KSEL ----
  const int b0 = t*64;
  uint32_t local = 0;
  {
    const uint4* h4 = (const uint4*)(hist + b0);
    #pragma unroll 4
    for (int q = 0; q < 16; ++q){ uint4 hv = h4[q]; local += hv.x + hv.y + hv.z + hv.w; }
  }
  uint32_t x = local;
  #pragma unroll
  for (int off = 1; off < 64; off <<= 1){
    uint32_t y = __shfl_up(x, off);
    if (lane >= off) x += y;
  }
  if (lane == 63) wsum[wv] = x;
  __syncthreads();
  if (t == 0){
    uint32_t cum = 0;
    for (int w = 0; w < 16; ++w){ woff[w] = cum; cum += wsum[w]; }
  }
  __syncthreads();
  uint32_t excl = x - local + woff[wv];       // exclusive prefix of this thread's 64 bins
  if (excl < KSEL && excl + local >= KSEL){   // unique crossing thread
    uint32_t cum = excl;
    for (int b = 0; b < 64; ++b){
      uint32_t h = hist[b0 + b];
      if (cum + h >= KSEL){ s_B = (uint32_t)(b0 + b); s_cumBelow = cum; break; }
      cum += h;
    }
  }
  __syncthreads();
  const uint32_t B = s_B;

  // ---- one pass over preds: sum exp over buckets > B; collect bucket-B candidates ----
  float sA = 0.f;
  const float4* p4 = (const float4*)preds;
  for (int i = t; i < 25000; i += 1024){
    float4 v = p4[i];
    float vv[4] = {v.x, v.y, v.z, v.w};
    #pragma unroll
    for (int e = 0; e < 4; ++e){
      uint32_t k = fmono(vv[e]);
      uint32_t bb = k >> 16;
      if (bb > B){
        sA += __expf(vv[e]);
      } else if (bb == B){
        uint32_t idx = atomicAdd(&candN, 1u);
        if (idx < CAND_CAP) cand[idx] = k;
      }
    }
  }
  #pragma unroll
  for (int off = 32; off; off >>= 1) sA += __shfl_xor(sA, off);
  if (lane == 0) zred[wv] = sA;
  __syncthreads();

  // ---- exact rank select among candidates (O(n^2), n ~ few hundred) ----
  const uint32_t n = candN < CAND_CAP ? candN : CAND_CAP;
  const uint32_t r = KSEL - s_cumBelow;       // 1-indexed rank within bucket
  for (uint32_t i = t; i < n; i += 1024){
    uint32_t ki = cand[i];
    uint32_t less = 0, eq = 0;
    for (uint32_t j = 0; j < n; ++j){
      uint32_t kj = cand[j];
      less += (kj < ki) ? 1u : 0u;
      eq   += (kj == ki) ? 1u : 0u;
    }
    if (less < r && r <= less + eq) s_keyT = ki;
  }
  __syncthreads();
  const uint32_t keyT = s_keyT;

  // ---- add exp of candidates strictly above keyT ----
  float sCA = 0.f;
  for (uint32_t i = t; i < n; i += 1024){
    uint32_t k = cand[i];
    if (k > keyT) sCA += __expf(finv(k));
  }
  #pragma unroll
  for (int off = 32; off; off >>= 1) sCA += __shfl_xor(sCA, off);
  if (lane == 0) zred[wv] += sCA;
  __syncthreads();
  if (t == 0){
    float Z = (float)KSEL;                    // exp(0)=1 for each of the KSEL zeroed entries
    for (int w = 0; w < 16; ++w) Z += zred[w];
    sc->keyT = keyT; sc->Z = Z;
  }
}

// ---------- k_prep3: 16 blocks — exact fp32 m_feats (f rows for the 2 argmax rows) ----------
__global__ void k_prep3(const float* __restrict__ preds, const float* __restrict__ feats,
                        const float* __restrict__ Wl, const float* __restrict__ bl,
                        const ull* __restrict__ cmax, const Scal* __restrict__ sc,
                        float* __restrict__ fmFw){
  __shared__ float fmX[2][512];
  __shared__ uint32_t s_mi[2];
  const int t = threadIdx.x;   // 256
  if (t < 2) s_mi[t] = ~(uint32_t)(cmax[t] & 0xffffffffull);
  __syncthreads();
  for (int i = t; i < 1024; i += 256){
    int j = i >> 9, col = i & 511;
    fmX[j][col] = feats[(size_t)s_mi[j]*DD + col];
  }
  __syncthreads();
  const int nn = blockIdx.x*32 + (t >> 3);
  const int h = t & 7;
  const float4* wr4 = (const float4*)(Wl + (size_t)nn*DD + h*64);
  const float4* x04 = (const float4*)(&fmX[0][h*64]);
  const float4* x14 = (const float4*)(&fmX[1][h*64]);
  float a0 = 0.f, a1 = 0.f;
  #pragma unroll
  for (int k = 0; k < 16; ++k){
    float4 w = wr4[k], u = x04[k], v = x14[k];
    a0 += u.x*w.x + u.y*w.y + u.z*w.z + u.w*w.w;
    a1 += v.x*w.x + v.y*w.y + v.z*w.z + v.w*w.w;
  }
  a0 += __shfl_xor(a0, 1); a0 += __shfl_xor(a0, 2); a0 += __shfl_xor(a0, 4);
  a1 += __shfl_xor(a1, 1); a1 += __shfl_xor(a1, 2); a1 += __shfl_xor(a1, 4);
  if (h == 0){
    uint32_t keyT = sc->keyT;
    float Z = sc->Z;
    float p0 = preds[s_mi[0]]; float q0 = (fmono(p0) <= keyT) ? 0.f : p0;
    float g0 = 1.f + __expf(q0) / Z;
    float p1 = preds[s_mi[1]]; float q1 = (fmono(p1) <= keyT) ? 0.f : p1;
    float g1 = 1.f + __expf(q1) / Z;
    float v0 = bl[nn] + g0*a0; fmFw[nn]       = v0 > 0.f ? v0 : 0.f;
    float v1 = bl[nn] + g1*a1; fmFw[512 + nn] = v1 > 0.f ? v1 : 0.f;
  }
}

// ---------- k_prep4: 2 blocks — q_max ----------
__global__ void k_prep4(const float* __restrict__ Wq, const float* __restrict__ bq,
                        const float* __restrict__ fmFw, float* __restrict__ qmv){
  __shared__ float xs[512];
  const int t = threadIdx.x;   // 256
  const int j = blockIdx.x;
  for (int i = t; i < 512; i += 256) xs[i] = fmFw[j*512 + i];
  __syncthreads();
  const int q = t >> 1, h = t & 1;
  const float4* wr4 = (const float4*)(Wq + (size_t)q*DD + h*256);
  const float4* x4  = (const float4*)(&xs[h*256]);
  float a = 0.f;
  #pragma unroll 4
  for (int k = 0; k < 64; ++k){
    float4 w = wr4[k], u = x4[k];
    a += u.x*w.x + u.y*w.y + u.z*w.z + u.w*w.w;
  }
  a += __shfl_xor(a, 1);
  if (h == 0) qmv[j*QD + q] = tanhf(bq[q] + a);
}

// ---------- k_fused v3: barrier-free K-loop; B direct from global (L2), A in LDS ----------
// Wave tile 64x32 (acc[4][2]); 4 waves cover the 128 chunk rows with no fetch duplication.
// LDS: AF [64][512] u16 swizzled (16B blk ^= row&7) = 64KB + sred 2KB -> 2 blocks/CU.
__launch_bounds__(256, 2)
__global__ void k_fused(const float* __restrict__ feats, const float* __restrict__ preds,
                        const u16* __restrict__ wch,
                        const float* __restrict__ bl, const float* __restrict__ bv,
                        const float* __restrict__ bq, const float* __restrict__ qmv,
                        const Scal* __restrict__ sc,
                        float* __restrict__ gpart, float* __restrict__ gpartE,
                        float* __restrict__ Aout){
  __shared__ __align__(16) u16 AF[32768];    // [64][512]
  __shared__ __align__(16) float sred[512];  // [64 rows][2 j][4 waves]
  const int tid = threadIdx.x;
  const int lane = tid & 63, quad = lane >> 4, l16 = lane & 15;
  const int wave = tid >> 6;
  const long i0 = (long)blockIdx.x * 64;
  const uint32_t keyT = sc->keyT;
  const float Z = sc->Z;

  // per-wave weight source: rows wave*32 + {n*16 + l16}, K slice quad*8
  const u16* bsrc = wch + (size_t)((wave*32 + l16)*32 + quad*8);
  uint4 pA0 = *(const uint4*)(bsrc);               // chunk 0
  uint4 pA1 = *(const uint4*)(bsrc + 512);
  uint4 pB0 = *(const uint4*)(bsrc + 4096);        // chunk 1
  uint4 pB1 = *(const uint4*)(bsrc + 4096 + 512);

  // ---- stage gX tile (64 x 512) into AF as bf16, g folded; row = lane; swizzled ----
  {
    int row = lane;
    long ir = i0 + row; if (ir >= NROWS) ir = NROWS - 1;
    float p = preds[ir];
    float pm = (fmono(p) <= keyT) ? 0.f : p;
    float g = 1.f + __expf(pm) / Z;
    const float4* src = (const float4*)(feats + ir*DD + wave*128);
    u16* dstrow = AF + row*512;
    const int swz = row & 7;
    #pragma unroll
    for (int j = 0; j < 16; ++j){
      float4 a = src[2*j], b = src[2*j + 1];
      uint4 pk;
      pk.x = pkbf(a.x*g, a.y*g); pk.y = pkbf(a.z*g, a.w*g);
      pk.z = pkbf(b.x*g, b.y*g); pk.w = pkbf(b.z*g, b.w*g);
      int blk = (wave << 4) | j;
      *(uint4*)&dstrow[(blk ^ swz) << 3] = pk;
    }
  }
  __syncthreads();   // AF visible to all waves

  const int sb = l16 & 7;
  f32x4 acc[4][2];
  uint32_t pkF[4][16];
  float eR0[4][4], eR1[4][4];
  int ci = 0;

#define KSTEP(P0, P1)                                                              \
  {                                                                                \
    bf16x8 b0 = __builtin_bit_cast(bf16x8, P0);                                    \
    bf16x8 b1 = __builtin_bit_cast(bf16x8, P1);                                    \
    if (ci + 2 < 144){                                                             \
      const u16* s_ = bsrc + (size_t)(ci + 2)*4096;                                \
      P0 = *(const uint4*)s_;                                                      \
      P1 = *(const uint4*)(s_ + 512);                                              \
    }                                                                              \
    int abk = ((((ci & 15) << 2) | quad) ^ sb) << 3;                               \
    bf16x8 a0 = *(const bf16x8*)&AF[(     l16)*512 + abk];                         \
    bf16x8 a1 = *(const bf16x8*)&AF[(16 + l16)*512 + abk];                         \
    bf16x8 a2 = *(const bf16x8*)&AF[(32 + l16)*512 + abk];                         \
    bf16x8 a3 = *(const bf16x8*)&AF[(48 + l16)*512 + abk];                         \
    acc[0][0] = MFMA16(a0, b0, acc[0][0]);                                         \
    acc[0][1] = MFMA16(a0, b1, acc[0][1]);                                         \
    acc[1][0] = MFMA16(a1, b0, acc[1][0]);                                         \
    acc[1][1] = MFMA16(a1, b1, acc[1][1]);                                         \
    acc[2][0] = MFMA16(a2, b0, acc[2][0]);                                         \
    acc[2][1] = MFMA16(a2, b1, acc[2][1]);                                         \
    acc[3][0] = MFMA16(a3, b0, acc[3][0]);                                         \
    acc[3][1] = MFMA16(a3, b1, acc[3][1]);                                         \
    ++ci;                                                                          \
  }

  // ---- stage 1: f = relu(gX @ Wl^T + bl) -> pkF registers ----
  for (int nt = 0; nt < 4; ++nt){
    #pragma unroll
    for (int mi = 0; mi < 4; ++mi)
      #pragma unroll
      for (int ni = 0; ni < 2; ++ni) acc[mi][ni] = (f32x4){0.f,0.f,0.f,0.f};
    for (int kh = 0; kh < 8; ++kh){
      KSTEP(pA0, pA1);
      KSTEP(pB0, pB1);
    }
    #pragma unroll
    for (int ni = 0; ni < 2; ++ni){
      float bb = bl[nt*128 + wave*32 + ni*16 + l16];
      #pragma unroll
      for (int mi = 0; mi < 4; ++mi){
        float e0 = acc[mi][ni][0] + bb; e0 = e0 > 0.f ? e0 : 0.f;
        float e1 = acc[mi][ni][1] + bb; e1 = e1 > 0.f ? e1 : 0.f;
        float e2 = acc[mi][ni][2] + bb; e2 = e2 > 0.f ? e2 : 0.f;
        float e3 = acc[mi][ni][3] + bb; e3 = e3 > 0.f ? e3 : 0.f;
        pkF[nt][mi*4 + ni*2 + 0] = pkbf(e0, e1);
        pkF[nt][mi*4 + ni*2 + 1] = pkbf(e2, e3);
      }
    }
  }

  __syncthreads();   // all stage-1 AF reads complete before overwrite
  // ---- transpose pkF (C-layout) -> F tile in AF (A-operand layout, swizzled) ----
  #pragma unroll
  for (int nt = 0; nt < 4; ++nt)
    #pragma unroll
    for (int mi = 0; mi < 4; ++mi)
      #pragma unroll
      for (int ni = 0; ni < 2; ++ni){
        int col = nt*128 + wave*32 + ni*16 + l16;
        int r0 = mi*16 + quad*4;
        uint32_t x = pkF[nt][mi*4 + ni*2], y = pkF[nt][mi*4 + ni*2 + 1];
        int cb = col >> 3, cw = col & 7;
        AF[(r0+0)*512 + ((cb ^ ((r0+0)&7)) << 3) + cw] = (u16)x;
        AF[(r0+1)*512 + ((cb ^ ((r0+1)&7)) << 3) + cw] = (u16)(x >> 16);
        AF[(r0+2)*512 + ((cb ^ ((r0+2)&7)) << 3) + cw] = (u16)y;
        AF[(r0+3)*512 + ((cb ^ ((r0+3)&7)) << 3) + cw] = (u16)(y >> 16);
      }
  __syncthreads();   // F tile visible

  // ---- stage 2: [Q|V] = f @ W^T ; Q first (nt2=0 -> e), then V weighted ----
  for (int nt2 = 0; nt2 < 5; ++nt2){
    #pragma unroll
    for (int mi = 0; mi < 4; ++mi)
      #pragma unroll
      for (int ni = 0; ni < 2; ++ni) acc[mi][ni] = (f32x4){0.f,0.f,0.f,0.f};
    for (int kh = 0; kh < 8; ++kh){
      KSTEP(pA0, pA1);
      KSTEP(pB0, pB1);
    }
    if (nt2 == 0){
      // ---- Q epilogue: tanh, dot with qmv, e = exp(score/sqrt(128)) ----
      float p0[4][4], p1[4][4];
      #pragma unroll
      for (int mi = 0; mi < 4; ++mi)
        #pragma unroll
        for (int e = 0; e < 4; ++e){ p0[mi][e] = 0.f; p1[mi][e] = 0.f; }
      #pragma unroll
      for (int ni = 0; ni < 2; ++ni){
        int qc = wave*32 + ni*16 + l16;
        float bqv = bq[qc], q0 = qmv[qc], q1 = qmv[QD + qc];
        #pragma unroll
        for (int mi = 0; mi < 4; ++mi)
          #pragma unroll
          for (int e = 0; e < 4; ++e){
            float tq = tanhf(acc[mi][ni][e] + bqv);
            p0[mi][e] += tq * q0;
            p1[mi][e] += tq * q1;
          }
      }
      #pragma unroll
      for (int off = 1; off <= 8; off <<= 1)
        #pragma unroll
        for (int mi = 0; mi < 4; ++mi)
          #pragma unroll
          for (int e = 0; e < 4; ++e){
            p0[mi][e] += __shfl_xor(p0[mi][e], off);
            p1[mi][e] += __shfl_xor(p1[mi][e], off);
          }
      if (l16 == 0){
        #pragma unroll
        for (int mi = 0; mi < 4; ++mi)
          #pragma unroll
          for (int e = 0; e < 4; ++e){
            int row = mi*16 + quad*4 + e;
            sred[row*8 + 0*4 + wave] = p0[mi][e];
            sred[row*8 + 1*4 + wave] = p1[mi][e];
          }
      }
      __syncthreads();   // sred complete
      #pragma unroll
      for (int mi = 0; mi < 4; ++mi)
        #pragma unroll
        for (int e = 0; e < 4; ++e){
          int row = mi*16 + quad*4 + e;
          bool valid = (i0 + row) < NROWS;
          float sv0 = (sred[row*8+0] + sred[row*8+1] + sred[row*8+2] + sred[row*8+3]) * 0.08838834764831845f;
          float sv1 = (sred[row*8+4] + sred[row*8+5] + sred[row*8+6] + sred[row*8+7]) * 0.08838834764831845f;
          eR0[mi][e] = valid ? __expf(sv0) : 0.f;
          eR1[mi][e] = valid ? __expf(sv1) : 0.f;
        }
      if (tid < 128){
        int row = tid >> 1, j = tid & 1;
        float sv = (sred[row*8 + j*4+0] + sred[row*8 + j*4+1] + sred[row*8 + j*4+2] + sred[row*8 + j*4+3])
                   * 0.08838834764831845f;
        bool valid = (i0 + row) < NROWS;
        float ev = valid ? __expf(sv) : 0.f;
        if (valid) Aout[(i0 + row)*2 + j] = ev;
        float t2 = ev;
        #pragma unroll
        for (int off = 2; off <= 32; off <<= 1) t2 += __shfl_xor(t2, off);
        if (lane < 2) gpartE[(size_t)blockIdx.x*4 + (tid >> 6)*2 + j] = t2;
      }
    } else {
      // ---- V epilogue: e-weighted column sums -> per-block gpart ----
      #pragma unroll
      for (int ni = 0; ni < 2; ++ni){
        int colv = (nt2 - 1)*128 + wave*32 + ni*16 + l16;
        float bvv = bv[colv];
        float b0 = 0.f, b1 = 0.f;
        #pragma unroll
        for (int mi = 0; mi < 4; ++mi)
          #pragma unroll
          for (int e = 0; e < 4; ++e){
            float v = acc[mi][ni][e] + bvv;
            b0 += v * eR0[mi][e];
            b1 += v * eR1[mi][e];
          }
        b0 += __shfl_xor(b0, 16); b0 += __shfl_xor(b0, 32);
        b1 += __shfl_xor(b1, 16); b1 += __shfl_xor(b1, 32);
        if (quad == 0){
          gpart[(size_t)blockIdx.x*1024 + colv]       = b0;
          gpart[(size_t)blockIdx.x*1024 + 512 + colv] = b1;
        }
      }
    }
  }
#undef KSTEP
}

// ---------- k_red: parallel reduce -> sumEV[1024], sumE[2] ----------
__global__ void k_red(const float* __restrict__ gpart, const float* __restrict__ gpartE,
                      float* __restrict__ sumEV, float* __restrict__ sumE){
  const int t = threadIdx.x;
  if (blockIdx.x == 256){
    __shared__ float r0[256], r1[256];
    float s0 = 0.f, s1 = 0.f;
    for (int i = t; i < NB*2; i += 256){ s0 += gpartE[(size_t)i*2]; s1 += gpartE[(size_t)i*2 + 1]; }
    r0[t] = s0; r1[t] = s1;
    __syncthreads();
    for (int st = 128; st; st >>= 1){
      if (t < st){ r0[t] += r0[t + st]; r1[t] += r1[t + st]; }
      __syncthreads();
    }
    if (t == 0){ sumE[0] = r0[0]; sumE[1] = r1[0]; }
    return;
  }
  __shared__ float4 red[256];
  int col4 = blockIdx.x * 4;
  float4 s = {0.f, 0.f, 0.f, 0.f};
  for (int r = t; r < NB; r += 256){
    float4 v = *(const float4*)(gpart + (size_t)r*1024 + col4);
    s.x += v.x; s.y += v.y; s.z += v.z; s.w += v.w;
  }
  red[t] = s;
  __syncthreads();
  for (int st = 128; st; st >>= 1){
    if (t < st){
      float4 o = red[t + st];
      red[t].x += o.x; red[t].y += o.y; red[t].z += o.z; red[t].w += o.w;
    }
    __syncthreads();
  }
  if (t == 0) *(float4*)(sumEV + col4) = red[0];
}

// ---------- k_post: normalize A; compute B and Cout ----------
__global__ void k_post(float* __restrict__ out, const float* __restrict__ sumE,
                       const float* __restrict__ sumEV, const float* __restrict__ Wfcc,
                       const float* __restrict__ bfcc){
  if (blockIdx.x < 782){
    int idx = blockIdx.x*256 + threadIdx.x;
    if (idx < 200000) out[2 + idx] = out[2 + idx] / sumE[idx & 1];
    return;
  }
  __shared__ float red[512];
  int t = threadIdx.x;
  float z0 = sumE[0], z1 = sumE[1];
  float c0 = 0.f, c1 = 0.f;
  for (int e = t; e < 1024; e += 256){
    float bvv = sumEV[e] / ((e >> 9) ? z1 : z0);
    out[200002 + e] = bvv;
    c0 += bvv * Wfcc[e];
    c1 += bvv * Wfcc[1024 + e];
  }
  red[t] = c0; red[256 + t] = c1;
  __syncthreads();
  for (int s = 128; s; s >>= 1){
    if (t < s){ red[t] += red[t + s]; red[256 + t] += red[256 + t + s]; }
    __syncthreads();
  }
  if (t == 0){ out[0] = red[0] + bfcc[0]; out[1] = red[256] + bfcc[1]; }
}

// ---------- launch ----------
extern "C" void kernel_launch(void* const* d_in, const int* in_sizes, int n_in,
                              void* d_out, int out_size, void* d_ws, size_t ws_size,
                              hipStream_t stream){
  (void)in_sizes; (void)n_in; (void)out_size; (void)ws_size;
  const float* feats = (const float*)d_in[0];
  const float* c     = (const float*)d_in[1];
  const float* preds = (const float*)d_in[2];
  const float* W_lin = (const float*)d_in[3];
  const float* b_lin = (const float*)d_in[4];
  const float* W_q   = (const float*)d_in[5];
  const float* b_q   = (const float*)d_in[6];
  const float* W_v   = (const float*)d_in[7];
  const float* b_v   = (const float*)d_in[8];
  const float* W_fcc = (const float*)d_in[9];
  const float* b_fcc = (const float*)d_in[10];
  float* out = (float*)d_out;
  char* ws = (char*)d_ws;

  // ws layout (bytes) — every region fully rewritten each call
  u16*   wch    = (u16*)(ws + 0);            // 1179648 (144 chunks x 8KB)
  Scal*  sc     = (Scal*)(ws + 1179648);     // 64       -> 1179712
  float* qmv    = (float*)(ws + 1179712);    // 1024     -> 1180736
  float* sumE   = (float*)(ws + 1180736);    // 64       -> 1180800
  float* sumEV  = (float*)(ws + 1180800);    // 4096     -> 1184896
  float* fmFw   = (float*)(ws + 1184896);    // 4096     -> 1188992
  float* gpartE = (float*)(ws + 1188992);    // 25088    -> 1214080
  float* gpart  = (float*)(ws + 1214080);    // 1563*1024*4 = 6402048 -> 7616128
  // prep-phase scratch OVERLAYS gpart (gpart is written only later, by k_fused)
  uint32_t* hist = (uint32_t*)(ws + 1214080);          // 65536*4 = 262144
  ull*      cmax = (ull*)(ws + 1214080 + 262144);      // 16

  k_conv <<<2304, 256, 0, stream>>>(W_lin, W_v, W_q, wch, hist, cmax);
  k_sel1 <<<256, 256, 0, stream>>>(preds, c, hist, cmax);
  k_prep2<<<1, 1024, 0, stream>>>(preds, hist, sc);
  k_prep3<<<16, 256, 0, stream>>>(preds, feats, W_lin, b_lin, cmax, sc, fmFw);
  k_prep4<<<2, 256, 0, stream>>>(W_q, b_q, fmFw, qmv);
  k_fused<<<NB, 256, 0, stream>>>(feats, preds, wch, b_lin, b_v, b_q,
                                  qmv, sc, gpart, gpartE, out + 2);
  k_red  <<<257, 256, 0, stream>>>(gpart, gpartE, sumEV, sumE);
  k_post <<<783, 256, 0, stream>>>(out, sumE, sumEV, W_fcc, b_fcc);
}